// Round 7
// baseline (285.686 us; speedup 1.0000x reference)
//
#include <hip/hip_runtime.h>
#include <stdint.h>

#define N_NODES 50000
#define CIN 128
#define CMID 128
#define COUT 32
#define KNB 27
#define EPSV 1e-5f

typedef __attribute__((ext_vector_type(4))) float f4v;
typedef __attribute__((ext_vector_type(8))) short s8v;
typedef __attribute__((ext_vector_type(4))) short s4v;

__device__ __forceinline__ unsigned short f2bf(float f) {
  union { float f; uint32_t u; } v; v.f = f;
  return (unsigned short)((v.u + 0x7FFFu + ((v.u >> 16) & 1u)) >> 16);  // RNE
}
__device__ __forceinline__ float bf2f(short s) {
  return __uint_as_float(((uint32_t)(uint16_t)s) << 16);
}

__device__ __forceinline__ f4v mfma16(s8v a, s8v b, f4v c) {
  return __builtin_amdgcn_mfma_f32_16x16x32_bf16(a, b, c, 0, 0, 0);
}

// async global->LDS, 16B/lane; dest wave-uniform base + lane*16, src per-lane.
__device__ __forceinline__ void gload_lds16(const void* g, void* lds) {
  __builtin_amdgcn_global_load_lds(
      (const __attribute__((address_space(1))) uint32_t*)(uintptr_t)g,
      (__attribute__((address_space(3))) uint32_t*)(uint32_t)(uintptr_t)lds,
      16, 0, 0);
}

// inline int64-vs-int32 detection (hi words of first 16 entries all 0/-1)
__device__ __forceinline__ bool neigh_is64(const void* neigh) {
  const int* p = (const int*)neigh;
  int ok = 1;
#pragma unroll
  for (int i = 0; i < 16; ++i) {
    int hi = p[2 * i + 1];
    if (hi != 0 && hi != -1) ok = 0;
  }
  return ok != 0;
}

// ---------------------------------------------------------------- transpose -
// neighT[k][row] int32 (empty -> N_NODES), via LDS tile transpose (coalesced).
__global__ __launch_bounds__(256) void k_transpose(
    const void* __restrict__ neigh, int* __restrict__ neighT)
{
  __shared__ int tT[KNB][257];
  const int r0 = blockIdx.x * 256;
  const bool is64 = neigh_is64(neigh);
  const int tid = threadIdx.x;
  for (int e = tid; e < 256 * KNB; e += 256) {
    int r = e / KNB, k = e - r * KNB;
    if (r0 + r < N_NODES) {
      long long v = is64 ? ((const long long*)neigh)[(size_t)r0 * KNB + e]
                         : (long long)((const int*)neigh)[(size_t)r0 * KNB + e];
      tT[k][r] = (v < 0) ? N_NODES : (int)v;
    }
  }
  __syncthreads();
  for (int e = tid; e < KNB * 256; e += 256) {
    int k = e >> 8, r = e & 255;
    if (r0 + r < N_NODES) neighT[(size_t)k * N_NODES + r0 + r] = tT[k][r];
  }
}

// ---------------------------------------------------------------- prep ------
// xb[(N+1)][128] bf16 (row N zeros)
// wt1f chunk ((k*4+kc)*8+n)*64+l = 8 bf16 {W1[k][kc*32+(l>>4)*8+e][n*16+(l&15)]}
// wt2f chunk (t*4+kc)*64+l, t=0..53 : 8 bf16 {W2[col>>5][kc*32+(l>>4)*8+e][col&31]}
//   with col = t*16 + (l&15)   (cols of the [128 x 864] W2cat matrix)
__global__ __launch_bounds__(256) void k_prep(
    const float* __restrict__ data, const float* __restrict__ W1,
    const float* __restrict__ W2,
    short* __restrict__ xb, short* __restrict__ wt1f, short* __restrict__ wt2f,
    float* __restrict__ gsums)
{
  const int TOT0 = (N_NODES + 1) * (CIN / 4);
  const int TOTW1 = KNB * 4 * 8 * 64;
  const int TOTW2 = 54 * 4 * 64;
  int gtid = blockIdx.x * 256 + threadIdx.x;
  int stride = gridDim.x * 256;
  for (int i = gtid; i < TOT0 + TOTW1 + TOTW2; i += stride) {
    if (i < TOT0) {
      int row = i >> 5, c4 = i & 31;
      s4v o = {};
      if (row < N_NODES) {
        f4v v = *(const f4v*)(data + (size_t)row * CIN + c4 * 4);
        o[0] = (short)f2bf(v[0]); o[1] = (short)f2bf(v[1]);
        o[2] = (short)f2bf(v[2]); o[3] = (short)f2bf(v[3]);
      }
      *(s4v*)(xb + (size_t)row * CIN + c4 * 4) = o;
    } else if (i < TOT0 + TOTW1) {
      int c = i - TOT0;
      int k = c >> 11, rem = c & 2047;
      int kc = rem >> 9, rem2 = rem & 511;
      int n = rem2 >> 6, l = rem2 & 63;
      int cin0 = kc * 32 + (l >> 4) * 8, cout = n * 16 + (l & 15);
      s8v o;
#pragma unroll
      for (int e = 0; e < 8; ++e)
        o[e] = (short)f2bf(W1[(size_t)k * (CIN * CMID) + (cin0 + e) * CMID + cout]);
      *(s8v*)(wt1f + (size_t)c * 8) = o;
    } else {
      int c = i - TOT0 - TOTW1;
      int l = c & 63, kc = (c >> 6) & 3, t = c >> 8;
      int col = t * 16 + (l & 15);
      int k = col >> 5, j = col & 31;
      int cin0 = kc * 32 + (l >> 4) * 8;
      s8v o;
#pragma unroll
      for (int e = 0; e < 8; ++e)
        o[e] = (short)f2bf(W2[(size_t)k * (CMID * COUT) + (cin0 + e) * COUT + j]);
      *(s8v*)(wt2f + (size_t)c * 8) = o;
    }
  }
  if (gtid < 64) gsums[gtid] = 0.0f;
}

// ---------------------------------------------------------------- conv1 -----
// M_block=128, 4 waves (wave = 32 rows x 128 cols), BK=128 (FULL k / step):
// 13/14 steps, ONE barrier each. 64 MFMA vs 18 VMEM per step. A direct to
// fragment regs one step ahead; idx two steps ahead.
__global__ __launch_bounds__(256, 2) void k_conv1(
    const short* __restrict__ xb, const int* __restrict__ neighT,
    const short* __restrict__ wt1f, short* __restrict__ x1p)
{
  __shared__ short Bs[2][16384];       // 2 x 32KB
  const int tid = threadIdx.x;
  const int l = tid & 63, w = tid >> 6;
  const int bx = blockIdx.x;
  const int kh = (bx >= 391) ? 1 : 0;
  const int rb = kh ? bx - 391 : bx;
  const int rw = rb * 128 + w * 32;
  const int k0 = kh ? 13 : 0, k1 = kh ? 27 : 13;
  const int S = k1 - k0;
  const int lr = l & 15, lho = l >> 4;

  int ra = rw + lr;       if (ra >= N_NODES) ra = N_NODES - 1;
  int rb2 = rw + 16 + lr; if (rb2 >= N_NODES) rb2 = N_NODES - 1;

  f4v acc[2][8] = {};
  s8v Ac[2][4], An[2][4];
  int ian = 0, ibn = 0, ia2 = 0, ib2 = 0;

  auto stageB = [&](int buf, int k) {
#pragma unroll
    for (int j = 0; j < 8; ++j) {
      int q = w * 8 + j;               // chunk 0..31 of this k's 32KB
      const short* src = wt1f + ((size_t)(k * 32 + q) << 9) + l * 8;
      gload_lds16(src, &Bs[buf][q * 512]);
    }
  };
  auto gatherA = [&](s8v A[2][4], int i0, int i1) {
    const short* p0 = xb + (size_t)i0 * CIN + lho * 8;
    const short* p1 = xb + (size_t)i1 * CIN + lho * 8;
#pragma unroll
    for (int kc = 0; kc < 4; ++kc) {
      A[0][kc] = *(const s8v*)(p0 + kc * 32);
      A[1][kc] = *(const s8v*)(p1 + kc * 32);
    }
  };
  auto compute = [&](int cb, s8v A[2][4]) {
#pragma unroll
    for (int kc = 0; kc < 4; ++kc) {
#pragma unroll
      for (int n = 0; n < 8; ++n) {
        s8v bf = *(const s8v*)&Bs[cb][(kc * 8 + n) * 512 + l * 8];
        acc[0][n] = mfma16(A[0][kc], bf, acc[0][n]);
        acc[1][n] = mfma16(A[1][kc], bf, acc[1][n]);
      }
    }
  };

  // prologue: k0 staged+gathered; idx(k0+1) preloaded
  {
    int iac = neighT[(size_t)k0 * N_NODES + ra];
    int ibc = neighT[(size_t)k0 * N_NODES + rb2];
    gatherA(Ac, iac, ibc);
  }
  if (S > 1) {
    ian = neighT[(size_t)(k0 + 1) * N_NODES + ra];
    ibn = neighT[(size_t)(k0 + 1) * N_NODES + rb2];
  }
  stageB(0, k0);
  __syncthreads();

  int cur = 0;
  for (int s = 0; s < S; ++s) {
    const int k = k0 + s;
    if (s + 1 < S) stageB(cur ^ 1, k + 1);       // next-k B (async LDS)
    if (s + 2 < S) {                             // idx two ahead (coalesced)
      ia2 = neighT[(size_t)(k + 2) * N_NODES + ra];
      ib2 = neighT[(size_t)(k + 2) * N_NODES + rb2];
    }
    if (s + 1 < S) gatherA(An, ian, ibn);        // next-k A gathers
    compute(cur, Ac);
    __syncthreads();
    ian = ia2; ibn = ib2;
#pragma unroll
    for (int kc = 0; kc < 4; ++kc) { Ac[0][kc] = An[0][kc]; Ac[1][kc] = An[1][kc]; }
    cur ^= 1;
  }

  short* xp = x1p + (size_t)kh * N_NODES * CMID;
#pragma unroll
  for (int rg = 0; rg < 2; ++rg) {
#pragma unroll
    for (int j = 0; j < 4; ++j) {
      int grow = rw + rg * 16 + lho * 4 + j;
      if (grow < N_NODES) {
#pragma unroll
        for (int n = 0; n < 8; ++n)
          xp[(size_t)grow * CMID + n * 16 + lr] = (short)f2bf(acc[rg][n][j]);
      }
    }
  }
}

// ---------------------------------------------------------------- sum -------
__global__ __launch_bounds__(256) void k_sum(
    const short* __restrict__ x1p, const float* __restrict__ b1,
    float* __restrict__ gsums)
{
  __shared__ float sh[64];
  const int tid = threadIdx.x;
  if (tid < 64) sh[tid] = 0.0f;
  __syncthreads();
  const int g = tid & 31;
  const short* p0 = x1p;
  const short* p1 = x1p + (size_t)N_NODES * CMID;
  f4v bv = *(const f4v*)(b1 + g * 4);
  float s = 0.f, ss = 0.f;
  for (int r = blockIdx.x * 8 + (tid >> 5); r < N_NODES; r += gridDim.x * 8) {
    s4v v0 = *(const s4v*)(p0 + (size_t)r * CMID + g * 4);
    s4v v1 = *(const s4v*)(p1 + (size_t)r * CMID + g * 4);
#pragma unroll
    for (int e = 0; e < 4; ++e) {
      float x = bf2f(v0[e]) + bf2f(v1[e]) + bv[e];
      s += x; ss += x * x;
    }
  }
  s += __shfl_xor(s, 32); ss += __shfl_xor(ss, 32);
  if ((tid & 32) == 0) { atomicAdd(&sh[g], s); atomicAdd(&sh[32 + g], ss); }
  __syncthreads();
  if (tid < 64) atomicAdd(&gsums[tid], sh[tid]);
}

// ---------------------------------------------------------------- GN+SiLU ---
__global__ __launch_bounds__(256) void k_gnsilu(
    const short* __restrict__ x1p, const float* __restrict__ b1,
    const float* __restrict__ gsums, const float* __restrict__ gn_w,
    const float* __restrict__ gn_b, short* __restrict__ xnb)
{
  const float invc = 1.0f / (N_NODES * 4.0f);
  const short* p0 = x1p;
  const short* p1 = x1p + (size_t)N_NODES * CMID;
  int gtid = blockIdx.x * 256 + threadIdx.x;
  int stride = gridDim.x * 256;
  const int TOT = N_NODES * (CMID / 4);
  for (int i = gtid; i < TOT; i += stride) {
    int row = i >> 5, g = i & 31;
    float mean = gsums[g] * invc;
    float var = gsums[32 + g] * invc - mean * mean;
    float rs = rsqrtf(var + EPSV);
    s4v v0 = *(const s4v*)(p0 + (size_t)row * CMID + g * 4);
    s4v v1 = *(const s4v*)(p1 + (size_t)row * CMID + g * 4);
    f4v bv = *(const f4v*)(b1 + g * 4);
    f4v wv = *(const f4v*)(gn_w + g * 4);
    f4v gv = *(const f4v*)(gn_b + g * 4);
    s4v o;
#pragma unroll
    for (int e = 0; e < 4; ++e) {
      float x = bf2f(v0[e]) + bf2f(v1[e]) + bv[e];
      float xn = (x - mean) * rs * wv[e] + gv[e];
      float y = xn / (1.0f + __expf(-xn));
      o[e] = (short)f2bf(y);
    }
    *(s4v*)(xnb + (size_t)row * CMID + g * 4) = o;
  }
}

// ---------------------------------------------------------------- proj ------
// Dense GEMM xn[50000,128] x W2cat[128, cols T0*16..(T0+NT)*16) -> c bf16.
// Full B-slab in LDS once, ZERO k-loop barriers. Wave = 32 rows.
template<int T0, int NT>
__global__ __launch_bounds__(256, 1) void k_proj(
    const short* __restrict__ xnb, const short* __restrict__ wt2f,
    short* __restrict__ cbuf)
{
  __shared__ short Ws[28 * 4 * 512];   // up to 112KB
  const int tid = threadIdx.x;
  const int l = tid & 63, w = tid >> 6;
  const int rw = blockIdx.x * 128 + w * 32;
  const int lr = l & 15, lho = l >> 4;
  const int NC = NT * 16;

  for (int q = w; q < NT * 4; q += 4)
    gload_lds16(wt2f + ((size_t)(T0 * 4 + q) << 9) + l * 8, &Ws[q * 512]);

  s8v a[2][4];
#pragma unroll
  for (int rs = 0; rs < 2; ++rs) {
    int row = rw + rs * 16 + lr; if (row >= N_NODES) row = N_NODES - 1;
    const short* p = xnb + (size_t)row * CMID + lho * 8;
#pragma unroll
    for (int kc = 0; kc < 4; ++kc) a[rs][kc] = *(const s8v*)(p + kc * 32);
  }
  __syncthreads();

  for (int t = 0; t < NT; ++t) {
    f4v acc[2] = {};
#pragma unroll
    for (int kc = 0; kc < 4; ++kc) {
      s8v bf = *(const s8v*)&Ws[(t * 4 + kc) * 512 + l * 8];
      acc[0] = mfma16(a[0][kc], bf, acc[0]);
      acc[1] = mfma16(a[1][kc], bf, acc[1]);
    }
#pragma unroll
    for (int rs = 0; rs < 2; ++rs) {
#pragma unroll
      for (int j = 0; j < 4; ++j) {
        int row = rw + rs * 16 + lho * 4 + j;
        if (row < N_NODES)
          cbuf[(size_t)row * NC + t * 16 + lr] = (short)f2bf(acc[rs][j]);
      }
    }
  }
}

// ---------------------------------------------------------------- gather2 ---
// out[n][j] (=bias+ / +=) sum_k c[neigh[n][k]][k*32+j]. 8 lanes/node, 8B/lane.
// Unconditional loads from row max(v,0) + mask -> full ILP (KC loads in flight).
template<int INIT, int KC, int KSTART>
__global__ __launch_bounds__(256) void k_gather2(
    const short* __restrict__ cbuf, const void* __restrict__ neigh,
    const float* __restrict__ b2, float* __restrict__ out)
{
  const int tid = threadIdx.x;
  const int n = blockIdx.x * 32 + (tid >> 3);
  const int l8 = tid & 7;
  if (n >= N_NODES) return;
  const bool is64 = neigh_is64(neigh);
  const int NC = KC * 32;

  int id[KC]; float msk[KC];
#pragma unroll
  for (int k = 0; k < KC; ++k) {
    long long v = is64 ? ((const long long*)neigh)[(size_t)n * KNB + KSTART + k]
                       : (long long)((const int*)neigh)[(size_t)n * KNB + KSTART + k];
    msk[k] = (v >= 0) ? 1.0f : 0.0f;
    id[k] = (v >= 0) ? (int)v : 0;
  }
  f4v acc;
  if (INIT) acc = *(const f4v*)(b2 + l8 * 4);
  else      acc = *(const f4v*)(out + (size_t)n * COUT + l8 * 4);
  s4v cv[KC];
#pragma unroll
  for (int k = 0; k < KC; ++k)
    cv[k] = *(const s4v*)(cbuf + (size_t)id[k] * NC + k * 32 + l8 * 4);
#pragma unroll
  for (int k = 0; k < KC; ++k) {
#pragma unroll
    for (int e = 0; e < 4; ++e) acc[e] += msk[k] * bf2f(cv[k][e]);
  }
  *(f4v*)(out + (size_t)n * COUT + l8 * 4) = acc;
}

// ---------------------------------------------------------------- launch ----
extern "C" void kernel_launch(void* const* d_in, const int* in_sizes, int n_in,
                              void* d_out, int out_size, void* d_ws, size_t ws_size,
                              hipStream_t stream) {
  const float* data = (const float*)d_in[0];
  const void* neigh = d_in[1];
  const float* W1   = (const float*)d_in[2];
  const float* b1   = (const float*)d_in[3];
  const float* gn_w = (const float*)d_in[4];
  const float* gn_b = (const float*)d_in[5];
  const float* W2   = (const float*)d_in[6];
  const float* b2   = (const float*)d_in[7];

  // region0 (45MB): conv1-phase [xb|wt1f|neighT|x1p] ... later aliased by cbuf
  char* p = (char*)d_ws;
  char* r0 = p;
  short* xb   = (short*)p; p += (size_t)(N_NODES + 1) * CIN * 2;   // 12.8MB
  short* wt1f = (short*)p; p += (size_t)KNB * CMID * CIN * 2;      // 884KB
  int*   neighT = (int*)p; p += (size_t)KNB * N_NODES * 4;         // 5.4MB
  short* x1p  = (short*)p; p += (size_t)2 * N_NODES * CMID * 2;    // 25.6MB
  p = r0 + ((size_t)N_NODES * 448 * 2 + 255 & ~(size_t)255);       // 44.8MB
  short* cbuf = (short*)r0;                                        // alias region0
  // region1: live across both phases
  short* xnb  = (short*)p; p += (size_t)N_NODES * CMID * 2;        // 12.8MB
  short* wt2f = (short*)p; p += (size_t)54 * 4 * 64 * 8 * 2;       // 221KB
  float* gsums = (float*)p;

  k_transpose<<<(N_NODES + 255) / 256, 256, 0, stream>>>(neigh, neighT);
  k_prep<<<2048, 256, 0, stream>>>(data, W1, W2, xb, wt1f, wt2f, gsums);
  k_conv1<<<782, 256, 0, stream>>>(xb, neighT, wt1f, x1p);
  k_sum<<<391, 256, 0, stream>>>(x1p, b1, gsums);
  k_gnsilu<<<1563, 256, 0, stream>>>(x1p, b1, gsums, gn_w, gn_b, xnb);
  // conv2 = projection-first, two k-passes sharing cbuf
  k_proj<0, 28><<<391, 256, 0, stream>>>(xnb, wt2f, cbuf);          // k 0..13
  k_gather2<1, 14, 0><<<1563, 256, 0, stream>>>(cbuf, neigh, b2, (float*)d_out);
  k_proj<28, 26><<<391, 256, 0, stream>>>(xnb, wt2f, cbuf);         // k 14..26
  k_gather2<0, 13, 14><<<1563, 256, 0, stream>>>(cbuf, neigh, b2, (float*)d_out);
}

// Round 8
// 243.578 us; speedup vs baseline: 1.1729x; 1.1729x over previous
//
#include <hip/hip_runtime.h>
#include <stdint.h>

#define N_NODES 50000
#define CIN 128
#define CMID 128
#define COUT 32
#define KNB 27
#define EPSV 1e-5f

typedef __attribute__((ext_vector_type(4))) float f4v;
typedef __attribute__((ext_vector_type(8))) short s8v;
typedef __attribute__((ext_vector_type(4))) short s4v;

__device__ __forceinline__ unsigned short f2bf(float f) {
  union { float f; uint32_t u; } v; v.f = f;
  return (unsigned short)((v.u + 0x7FFFu + ((v.u >> 16) & 1u)) >> 16);  // RNE
}
__device__ __forceinline__ float bf2f(short s) {
  return __uint_as_float(((uint32_t)(uint16_t)s) << 16);
}

__device__ __forceinline__ f4v mfma16(s8v a, s8v b, f4v c) {
  return __builtin_amdgcn_mfma_f32_16x16x32_bf16(a, b, c, 0, 0, 0);
}

// async global->LDS, 16B/lane; dest wave-uniform base + lane*16, src per-lane.
__device__ __forceinline__ void gload_lds16(const void* g, void* lds) {
  __builtin_amdgcn_global_load_lds(
      (const __attribute__((address_space(1))) uint32_t*)(uintptr_t)g,
      (__attribute__((address_space(3))) uint32_t*)(uint32_t)(uintptr_t)lds,
      16, 0, 0);
}

// inline int64-vs-int32 detection (hi words of first 16 entries all 0/-1)
__device__ __forceinline__ bool neigh_is64(const void* neigh) {
  const int* p = (const int*)neigh;
  int ok = 1;
#pragma unroll
  for (int i = 0; i < 16; ++i) {
    int hi = p[2 * i + 1];
    if (hi != 0 && hi != -1) ok = 0;
  }
  return ok != 0;
}

// ---------------------------------------------------------------- transpose -
// neighT[k][row] int32 (empty -> N_NODES), via LDS tile transpose (coalesced).
__global__ __launch_bounds__(256) void k_transpose(
    const void* __restrict__ neigh, int* __restrict__ neighT)
{
  __shared__ int tT[KNB][257];
  const int r0 = blockIdx.x * 256;
  const bool is64 = neigh_is64(neigh);
  const int tid = threadIdx.x;
  for (int e = tid; e < 256 * KNB; e += 256) {
    int r = e / KNB, k = e - r * KNB;
    if (r0 + r < N_NODES) {
      long long v = is64 ? ((const long long*)neigh)[(size_t)r0 * KNB + e]
                         : (long long)((const int*)neigh)[(size_t)r0 * KNB + e];
      tT[k][r] = (v < 0) ? N_NODES : (int)v;
    }
  }
  __syncthreads();
  for (int e = tid; e < KNB * 256; e += 256) {
    int k = e >> 8, r = e & 255;
    if (r0 + r < N_NODES) neighT[(size_t)k * N_NODES + r0 + r] = tT[k][r];
  }
}

// ---------------------------------------------------------------- prep_x ----
// xb[(N+1)][128] bf16 (row N zeros); zero gsums.
__global__ __launch_bounds__(256) void k_prep_x(
    const float* __restrict__ data, short* __restrict__ xb,
    float* __restrict__ gsums)
{
  const int TOT0 = (N_NODES + 1) * (CIN / 4);
  int gtid = blockIdx.x * 256 + threadIdx.x;
  int stride = gridDim.x * 256;
  for (int i = gtid; i < TOT0; i += stride) {
    int row = i >> 5, c4 = i & 31;
    s4v o = {};
    if (row < N_NODES) {
      f4v v = *(const f4v*)(data + (size_t)row * CIN + c4 * 4);
      o[0] = (short)f2bf(v[0]); o[1] = (short)f2bf(v[1]);
      o[2] = (short)f2bf(v[2]); o[3] = (short)f2bf(v[3]);
    }
    *(s4v*)(xb + (size_t)row * CIN + c4 * 4) = o;
  }
  if (gtid < 64) gsums[gtid] = 0.0f;
}

// ---------------------------------------------------------------- prep_w ----
// Per-k LDS transpose of W1/W2 -> MFMA B-fragment order, all reads/writes
// coalesced (the old scalar path did ~280MB of strided line traffic).
//   wt1f chunk ((k*4+kc)*8+n)*64+l = 8 bf16 {W1[k][kc*32+(l>>4)*8+e][n*16+(l&15)]}
//   wt2f chunk ((k*4+kc)*2+n)*64+l = 8 bf16 {W2[k][kc*32+(l>>4)*8+e][n*16+(l&15)]}
__global__ __launch_bounds__(256) void k_prep_w(
    const float* __restrict__ W1, const float* __restrict__ W2,
    short* __restrict__ wt1f, short* __restrict__ wt2f)
{
  __shared__ short T1[128][136];   // T1[cout][cin]
  __shared__ short T2[32][136];    // T2[cout][cin]
  const int k = blockIdx.x;        // 0..26
  const int tid = threadIdx.x;

  const float* w1p = W1 + (size_t)k * (CIN * CMID);
  for (int i = tid; i < CIN * CMID / 4; i += 256) {     // coalesced 16B reads
    int c = i >> 5, d4 = i & 31;                        // c=cin, d=cout
    f4v v = *(const f4v*)(w1p + c * CMID + d4 * 4);
#pragma unroll
    for (int j = 0; j < 4; ++j) T1[d4 * 4 + j][c] = (short)f2bf(v[j]);
  }
  const float* w2p = W2 + (size_t)k * (CMID * COUT);
  for (int i = tid; i < CMID * COUT / 4; i += 256) {
    int c = i >> 3, d4 = i & 7;
    f4v v = *(const f4v*)(w2p + c * COUT + d4 * 4);
#pragma unroll
    for (int j = 0; j < 4; ++j) T2[d4 * 4 + j][c] = (short)f2bf(v[j]);
  }
  __syncthreads();

  for (int q = tid; q < 2048; q += 256) {               // wt1f: 16B ds_read + 16B store
    int l = q & 63, n = (q >> 6) & 7, kc = q >> 9;
    int cin0 = kc * 32 + ((l >> 4) << 3), cout = n * 16 + (l & 15);
    s8v v = *(const s8v*)&T1[cout][cin0];
    *(s8v*)(wt1f + ((size_t)k * 2048 + q) * 8) = v;
  }
  for (int q = tid; q < 512; q += 256) {                // wt2f
    int l = q & 63, n = (q >> 6) & 1, kc = q >> 7;
    int cin0 = kc * 32 + ((l >> 4) << 3), cout = n * 16 + (l & 15);
    s8v v = *(const s8v*)&T2[cout][cin0];
    *(s8v*)(wt2f + ((size_t)k * 512 + q) * 8) = v;
  }
}

// ---------------------------------------------------------------- conv1 -----
// r4 structure (best measured): M_block=128, 4 waves (wave = 32 rows x 128
// cols), BK=64, kh-split 2. B: LDS dbuf via global_load_lds. A: gather->regs,
// ds_write to wave-private swizzled LDS; one barrier per half-k step.
__global__ __launch_bounds__(256, 2) void k_conv1(
    const short* __restrict__ xb, const int* __restrict__ neighT,
    const short* __restrict__ wt1f, short* __restrict__ x1p)
{
  __shared__ short Bs[2][8192];        // 2 x 16KB
  __shared__ short As[4][2][2048];     // per-wave 2 x 4KB (32 rows x 128B)
  const int tid = threadIdx.x;
  const int l = tid & 63, w = tid >> 6;
  const int bx = blockIdx.x;
  const int kh = (bx >= 391) ? 1 : 0;
  const int rb = kh ? bx - 391 : bx;
  const int rw = rb * 128 + w * 32;    // wave's first row
  const int k0 = kh ? 13 : 0, k1 = kh ? 27 : 13;
  const int lr = l & 15, lho = l >> 4; // frag row / 8-elem group
  const int l8 = l >> 3, ls = l & 7;   // gather: row-in-8 / 16B slot

  f4v acc[2][8] = {};
  int idx[4], idxn[4];
  s8v ga[4];

  auto loadIdx = [&](int* id, int k) {
#pragma unroll
    for (int q = 0; q < 4; ++q) {
      int r = rw + q * 8 + l8; if (r >= N_NODES) r = N_NODES - 1;
      id[q] = neighT[(size_t)k * N_NODES + r];
    }
  };
  auto stageB = [&](int buf, int k, int h) {
    const short* src = wt1f + ((size_t)(k * 4 + h * 2) * 8) * 512 + l * 8;
#pragma unroll
    for (int j = 0; j < 4; ++j)
      gload_lds16(src + (w * 4 + j) * 512, &Bs[buf][(w * 4 + j) * 512]);
  };
  auto gatherA = [&](const int* id, int h) {
#pragma unroll
    for (int q = 0; q < 4; ++q)
      ga[q] = *(const s8v*)(xb + (size_t)id[q] * CIN + h * 64 + ls * 8);
  };
  auto writeA = [&](int buf) {
#pragma unroll
    for (int q = 0; q < 4; ++q)
      *(s8v*)&As[w][buf][(q * 8 + l8) * 64 + ((ls ^ l8) * 8)] = ga[q];
  };
  auto compute = [&](int cb) {
#pragma unroll
    for (int kc = 0; kc < 2; ++kc) {
      s8v af[2];
#pragma unroll
      for (int rg = 0; rg < 2; ++rg) {
        int row = rg * 16 + lr;
        af[rg] = *(const s8v*)&As[w][cb][row * 64 + (((kc * 4 + lho) ^ (lr & 7)) * 8)];
      }
#pragma unroll
      for (int n = 0; n < 8; ++n) {
        s8v bf = *(const s8v*)&Bs[cb][(kc * 8 + n) * 512 + l * 8];
        acc[0][n] = mfma16(af[0], bf, acc[0][n]);
        acc[1][n] = mfma16(af[1], bf, acc[1][n]);
      }
    }
  };

  // prologue: step (k0, h=0) into buf 0
  loadIdx(idx, k0);
  stageB(0, k0, 0);
  gatherA(idx, 0);
  __syncthreads();
  writeA(0);

  int cur = 0;
  for (int k = k0; k < k1; ++k) {
    const bool more = (k + 1 < k1);
    stageB(cur ^ 1, k, 1);
    gatherA(idx, 1);
    if (more) loadIdx(idxn, k + 1);
    compute(cur);
    __syncthreads();
    writeA(cur ^ 1);
    cur ^= 1;
    if (more) { stageB(cur ^ 1, k + 1, 0); gatherA(idxn, 0); }
    compute(cur);
    __syncthreads();
    if (more) {
      writeA(cur ^ 1);
#pragma unroll
      for (int q = 0; q < 4; ++q) idx[q] = idxn[q];
    }
    cur ^= 1;
  }

  short* xp = x1p + (size_t)kh * N_NODES * CMID;
#pragma unroll
  for (int rg = 0; rg < 2; ++rg) {
#pragma unroll
    for (int j = 0; j < 4; ++j) {
      int grow = rw + rg * 16 + lho * 4 + j;
      if (grow < N_NODES) {
#pragma unroll
        for (int n = 0; n < 8; ++n)
          xp[(size_t)grow * CMID + n * 16 + lr] = (short)f2bf(acc[rg][n][j]);
      }
    }
  }
}

// ---------------------------------------------------------------- sum -------
__global__ __launch_bounds__(256) void k_sum(
    const short* __restrict__ x1p, const float* __restrict__ b1,
    float* __restrict__ gsums)
{
  __shared__ float sh[64];
  const int tid = threadIdx.x;
  if (tid < 64) sh[tid] = 0.0f;
  __syncthreads();
  const int g = tid & 31;
  const short* p0 = x1p;
  const short* p1 = x1p + (size_t)N_NODES * CMID;
  f4v bv = *(const f4v*)(b1 + g * 4);
  float s = 0.f, ss = 0.f;
  for (int r = blockIdx.x * 8 + (tid >> 5); r < N_NODES; r += gridDim.x * 8) {
    s4v v0 = *(const s4v*)(p0 + (size_t)r * CMID + g * 4);
    s4v v1 = *(const s4v*)(p1 + (size_t)r * CMID + g * 4);
#pragma unroll
    for (int e = 0; e < 4; ++e) {
      float x = bf2f(v0[e]) + bf2f(v1[e]) + bv[e];
      s += x; ss += x * x;
    }
  }
  s += __shfl_xor(s, 32); ss += __shfl_xor(ss, 32);
  if ((tid & 32) == 0) { atomicAdd(&sh[g], s); atomicAdd(&sh[32 + g], ss); }
  __syncthreads();
  if (tid < 64) atomicAdd(&gsums[tid], sh[tid]);
}

// ---------------------------------------------------------------- GN+SiLU ---
__global__ __launch_bounds__(256) void k_gnsilu(
    const short* __restrict__ x1p, const float* __restrict__ b1,
    const float* __restrict__ gsums, const float* __restrict__ gn_w,
    const float* __restrict__ gn_b, short* __restrict__ xnb)
{
  const float invc = 1.0f / (N_NODES * 4.0f);
  const short* p0 = x1p;
  const short* p1 = x1p + (size_t)N_NODES * CMID;
  int gtid = blockIdx.x * 256 + threadIdx.x;
  int stride = gridDim.x * 256;
  const int TOT = (N_NODES + 1) * (CMID / 4);
  for (int i = gtid; i < TOT; i += stride) {
    int row = i >> 5, g = i & 31;
    s4v o = {};
    if (row < N_NODES) {
      float mean = gsums[g] * invc;
      float var = gsums[32 + g] * invc - mean * mean;
      float rs = rsqrtf(var + EPSV);
      s4v v0 = *(const s4v*)(p0 + (size_t)row * CMID + g * 4);
      s4v v1 = *(const s4v*)(p1 + (size_t)row * CMID + g * 4);
      f4v bv = *(const f4v*)(b1 + g * 4);
      f4v wv = *(const f4v*)(gn_w + g * 4);
      f4v gv = *(const f4v*)(gn_b + g * 4);
#pragma unroll
      for (int e = 0; e < 4; ++e) {
        float x = bf2f(v0[e]) + bf2f(v1[e]) + bv[e];
        float xn = (x - mean) * rs * wv[e] + gv[e];
        float y = xn / (1.0f + __expf(-xn));
        o[e] = (short)f2bf(y);
      }
    }
    *(s4v*)(xnb + (size_t)row * CMID + g * 4) = o;   // row N stays zeros
  }
}

// ---------------------------------------------------------------- conv2 -----
// r4 structure: M_block=128, wave = 32 rows x 32 cols, BK=64, kh-split 2.
// f32 partials (combined with bias in k_fin).
__global__ __launch_bounds__(256, 4) void k_conv2(
    const short* __restrict__ xnb, const int* __restrict__ neighT,
    const short* __restrict__ wt2f, float* __restrict__ x2p)
{
  __shared__ short Bs[2][2048];        // 2 x 4KB
  __shared__ short As[4][2][2048];
  const int tid = threadIdx.x;
  const int l = tid & 63, w = tid >> 6;
  const int bx = blockIdx.x;
  const int kh = (bx >= 391) ? 1 : 0;
  const int rb = kh ? bx - 391 : bx;
  const int rw = rb * 128 + w * 32;
  const int k0 = kh ? 13 : 0, k1 = kh ? 27 : 13;
  const int lr = l & 15, lho = l >> 4;
  const int l8 = l >> 3, ls = l & 7;

  f4v acc[2][2] = {};
  int idx[4], idxn[4];
  s8v ga[4];

  auto loadIdx = [&](int* id, int k) {
#pragma unroll
    for (int q = 0; q < 4; ++q) {
      int r = rw + q * 8 + l8; if (r >= N_NODES) r = N_NODES - 1;
      id[q] = neighT[(size_t)k * N_NODES + r];
    }
  };
  auto stageB = [&](int buf, int k, int h) {
    const short* src = wt2f + ((size_t)(k * 4 + h * 2) * 2) * 512 + l * 8;
    gload_lds16(src + w * 512, &Bs[buf][w * 512]);
  };
  auto gatherA = [&](const int* id, int h) {
#pragma unroll
    for (int q = 0; q < 4; ++q)
      ga[q] = *(const s8v*)(xnb + (size_t)id[q] * CMID + h * 64 + ls * 8);
  };
  auto writeA = [&](int buf) {
#pragma unroll
    for (int q = 0; q < 4; ++q)
      *(s8v*)&As[w][buf][(q * 8 + l8) * 64 + ((ls ^ l8) * 8)] = ga[q];
  };
  auto compute = [&](int cb) {
#pragma unroll
    for (int kc = 0; kc < 2; ++kc) {
      s8v af[2];
#pragma unroll
      for (int rg = 0; rg < 2; ++rg) {
        int row = rg * 16 + lr;
        af[rg] = *(const s8v*)&As[w][cb][row * 64 + (((kc * 4 + lho) ^ (lr & 7)) * 8)];
      }
#pragma unroll
      for (int n = 0; n < 2; ++n) {
        s8v bf = *(const s8v*)&Bs[cb][(kc * 2 + n) * 512 + l * 8];
        acc[0][n] = mfma16(af[0], bf, acc[0][n]);
        acc[1][n] = mfma16(af[1], bf, acc[1][n]);
      }
    }
  };

  loadIdx(idx, k0);
  stageB(0, k0, 0);
  gatherA(idx, 0);
  __syncthreads();
  writeA(0);

  int cur = 0;
  for (int k = k0; k < k1; ++k) {
    const bool more = (k + 1 < k1);
    stageB(cur ^ 1, k, 1);
    gatherA(idx, 1);
    if (more) loadIdx(idxn, k + 1);
    compute(cur);
    __syncthreads();
    writeA(cur ^ 1);
    cur ^= 1;
    if (more) { stageB(cur ^ 1, k + 1, 0); gatherA(idxn, 0); }
    compute(cur);
    __syncthreads();
    if (more) {
      writeA(cur ^ 1);
#pragma unroll
      for (int q = 0; q < 4; ++q) idx[q] = idxn[q];
    }
    cur ^= 1;
  }

  float* xp = x2p + (size_t)kh * N_NODES * COUT;
#pragma unroll
  for (int rg = 0; rg < 2; ++rg) {
#pragma unroll
    for (int j = 0; j < 4; ++j) {
      int grow = rw + rg * 16 + lho * 4 + j;
      if (grow < N_NODES) {
#pragma unroll
        for (int n = 0; n < 2; ++n)
          xp[(size_t)grow * COUT + n * 16 + lr] = acc[rg][n][j];
      }
    }
  }
}

// ---------------------------------------------------------------- fin -------
__global__ __launch_bounds__(256) void k_fin(
    const float* __restrict__ x2p, const float* __restrict__ b2,
    float* __restrict__ out)
{
  int i = blockIdx.x * 256 + threadIdx.x;
  const int TOT = N_NODES * COUT / 4;
  if (i < TOT) {
    int c4 = i & 7;
    f4v a = *(const f4v*)(x2p + (size_t)i * 4);
    f4v b = *(const f4v*)(x2p + (size_t)N_NODES * COUT + (size_t)i * 4);
    f4v bias = *(const f4v*)(b2 + c4 * 4);
    f4v o = a + b + bias;
    *(f4v*)(out + (size_t)i * 4) = o;
  }
}

// ---------------------------------------------------------------- launch ----
extern "C" void kernel_launch(void* const* d_in, const int* in_sizes, int n_in,
                              void* d_out, int out_size, void* d_ws, size_t ws_size,
                              hipStream_t stream) {
  const float* data = (const float*)d_in[0];
  const void* neigh = d_in[1];
  const float* W1   = (const float*)d_in[2];
  const float* b1   = (const float*)d_in[3];
  const float* gn_w = (const float*)d_in[4];
  const float* gn_b = (const float*)d_in[5];
  const float* W2   = (const float*)d_in[6];
  const float* b2   = (const float*)d_in[7];

  char* p = (char*)d_ws;
  short* xb   = (short*)p; p += (size_t)(N_NODES + 1) * CIN * 2;   // 12.8MB
  float* x2p  = (float*)xb;                 // alias: xb dead before conv2
  short* wt1f = (short*)p; p += (size_t)KNB * CMID * CIN * 2;      // 884KB
  short* wt2f = (short*)p; p += (size_t)KNB * COUT * CMID * 2;     // 221KB
  short* x1p  = (short*)p; p += (size_t)2 * N_NODES * CMID * 2;    // 25.6MB
  short* xnb  = (short*)p; p += (size_t)(N_NODES + 1) * CMID * 2;  // 12.8MB
  int*   neighT = (int*)p; p += (size_t)KNB * N_NODES * 4;         // 5.4MB
  float* gsums = (float*)p;

  k_transpose<<<(N_NODES + 255) / 256, 256, 0, stream>>>(neigh, neighT);
  k_prep_x<<<2048, 256, 0, stream>>>(data, xb, gsums);
  k_prep_w<<<KNB, 256, 0, stream>>>(W1, W2, wt1f, wt2f);
  k_conv1<<<782, 256, 0, stream>>>(xb, neighT, wt1f, x1p);
  k_sum<<<391, 256, 0, stream>>>(x1p, b1, gsums);
  k_gnsilu<<<2048, 256, 0, stream>>>(x1p, b1, gsums, gn_w, gn_b, xnb);
  k_conv2<<<782, 256, 0, stream>>>(xnb, neighT, wt2f, x2p);
  k_fin<<<(N_NODES * COUT / 4 + 255) / 256, 256, 0, stream>>>(x2p, b2, (float*)d_out);
}